// Round 15
// baseline (215.558 us; speedup 1.0000x reference)
//
#include <hip/hip_runtime.h>

// Problem constants
#define B_  2
#define S_  2048
#define D_  1024
#define H_  16
#define HD_ 64
#define M_  (B_*S_)   // 4096

typedef __attribute__((ext_vector_type(8))) short  short8;   // 8 bf16 (4 VGPRs)
typedef __attribute__((ext_vector_type(4))) float  float4v;  // 4 fp32
typedef __attribute__((ext_vector_type(4))) int    int4v;    // 16B

// 1/sqrt(D) * log2(e): softmax via native exp2 (v_exp_f32)
#define PSCALE 0.0450843341f   // (1/32) * 1.4426950408889634

__device__ __forceinline__ unsigned int pack2_bf16(float a, float b) {
#if __has_builtin(__builtin_amdgcn_cvt_pk_bf16_f32)
    auto p = __builtin_amdgcn_cvt_pk_bf16_f32(a, b);   // 1 VALU op, RNE
    return __builtin_bit_cast(unsigned int, p);
#else
    unsigned int xa = __builtin_bit_cast(unsigned int, a);
    unsigned int xb = __builtin_bit_cast(unsigned int, b);
    xa += 0x7fffu + ((xa >> 16) & 1u);
    xb += 0x7fffu + ((xb >> 16) & 1u);
    return (xa >> 16) | (xb & 0xffff0000u);
#endif
}
__device__ __forceinline__ unsigned short f_to_bf16bits(float f) {
#if __has_builtin(__builtin_amdgcn_cvt_pk_bf16_f32)
    return (unsigned short)(pack2_bf16(f, f) & 0xffffu);
#else
    unsigned int x = __builtin_bit_cast(unsigned int, f);
    x += 0x7fffu + ((x >> 16) & 1u);
    return (unsigned short)(x >> 16);
#endif
}

__device__ __forceinline__ float fast_exp2(float x) {
#if __has_builtin(__builtin_amdgcn_exp2f)
    return __builtin_amdgcn_exp2f(x);
#else
    return exp2f(x);
#endif
}

// Async global->LDS copy, 16B per lane. HW semantics: LDS dest = WAVE-UNIFORM
// base + lane*16; global src is PER-LANE. Caller passes the uniform LDS base.
__device__ __forceinline__ void async_cp16(const unsigned short* gsrc,
                                           unsigned short* lds_base_uniform) {
#if __has_builtin(__builtin_amdgcn_global_load_lds)
    __builtin_amdgcn_global_load_lds(
        (const __attribute__((address_space(1))) unsigned int*)gsrc,
        (__attribute__((address_space(3))) unsigned int*)lds_base_uniform,
        16, 0, 0);
#else
    const int lane = (int)(threadIdx.x & 63);
    *(int4v*)(lds_base_uniform + lane * 8) = *(const int4v*)gsrc;
#endif
}

// ---------------------------------------------------------------------------
// fp32 -> bf16 bulk convert: X(4M) + Wq,Wk,Wv,Wo (1M each). 8 elems/thread.
// ---------------------------------------------------------------------------
__global__ __launch_bounds__(256) void cvt_bf16(
    const float* __restrict__ X,  const float* __restrict__ Wq,
    const float* __restrict__ Wk, const float* __restrict__ Wv,
    const float* __restrict__ Wo,
    unsigned short* __restrict__ Xb,  unsigned short* __restrict__ Wqb,
    unsigned short* __restrict__ Wkb, unsigned short* __restrict__ Wvb,
    unsigned short* __restrict__ Wob)
{
    const long t = (long)blockIdx.x * 256 + threadIdx.x;
    const long e = t * 8;
    const float* src; unsigned short* dst; long off;
    if      (e < 4194304) { src = X;  dst = Xb;  off = e; }
    else if (e < 5242880) { src = Wq; dst = Wqb; off = e - 4194304; }
    else if (e < 6291456) { src = Wk; dst = Wkb; off = e - 5242880; }
    else if (e < 7340032) { src = Wv; dst = Wvb; off = e - 6291456; }
    else                  { src = Wo; dst = Wob; off = e - 7340032; }
    float4v a = *(const float4v*)&src[off];
    float4v b = *(const float4v*)&src[off + 4];
    int4v o;
    o[0] = (int)pack2_bf16(a[0], a[1]);
    o[1] = (int)pack2_bf16(a[2], a[3]);
    o[2] = (int)pack2_bf16(b[0], b[1]);
    o[3] = (int)pack2_bf16(b[2], b[3]);
    *(int4v*)&dst[off] = o;
}

// ---------------------------------------------------------------------------
// NT GEMM (R15): 128x64 tile, BK=64, global_load_lds, now 2-PHASE PIPELINED
// (T3/T4 minimum recipe). R14 diagnosis: the old loop issued staging loads
// and IMMEDIATELY drained them (vmcnt(0) at the 2nd barrier) -- zero
// prefetch distance, ~200-500cy exposed latency per K-step (the "1-phase"
// anti-pattern; catalog: 1ph vs pipelined = -28-41%). New loop:
//   prologue: STAGE(buf0, t=0); barrier
//   for t:  STAGE(buf^1, t+1); compute buf; barrier  // drain AFTER compute
// The barrier's implicit vmcnt(0) now waits on loads that had the whole
// ds_read+MFMA phase (~300-400cy) to land. One barrier per K-step. WAR-safe:
// barrier at end of t-1 means nobody still reads buf[(t+1)&1] at t's writes.
// LDS 48 KB dbuf -> 3 WG/CU (2ph reference kernels win even at 1 WG/CU --
// pipeline beats TLP once the drain is off the critical path).
// XCD-chunked swizzle kept from R14 (neutral, free).
// mode 0: Q  out[((b*H+h)*S+s)*HD+hd] * PSCALE
// mode 1: K  same layout, unscaled
// mode 2: Vt out[((b*H+h)*HD+hd)*S+s] -- operands SWAPPED (A=Wv, B=X)
// mode 3: fp32 row-major out[m*D+n]
// ---------------------------------------------------------------------------
__global__ __launch_bounds__(256) void gemm_bt(
    const unsigned short* __restrict__ A,
    const unsigned short* __restrict__ B0,
    const unsigned short* __restrict__ B1,
    const unsigned short* __restrict__ B2,
    void* __restrict__ O0, void* __restrict__ O1, void* __restrict__ O2,
    int mode_base)
{
    const int K = 1024;
    const int NT = K / 64;      // 16 K-steps
    const int z = blockIdx.z;
    const int mode = mode_base + z;
    const unsigned short* Aop;
    const unsigned short* Bop;
    void* Op = (z == 0) ? O0 : (z == 1) ? O1 : O2;

    // XCD-chunked bijective swizzle within this z-slice (nwg=512, %8==0)
    const int flat = blockIdx.y * gridDim.x + blockIdx.x;   // 0..511
    const int swz  = (flat & 7) * 64 + (flat >> 3);         // bijective

    int m0, n0;
    if (mode == 2) {            // swapped: A=Wv (rows=out-dim), B=X (rows=s)
        Aop = B2; Bop = A;
        m0 = (swz & 7) * 128;                            // 8 m-tiles (1024)
        n0 = (swz >> 3) * 64;                            // 64 n-tiles (4096)
    } else {
        Aop = A;
        Bop = (z == 0) ? B0 : (z == 1) ? B1 : B2;
        m0 = (swz >> 4) * 128;                           // 32 m-tiles (4096)
        n0 = (swz & 15) * 64;                            // 16 n-tiles (1024)
    }

    __shared__ alignas(16) unsigned short As[2][128 * 64];   // 32 KB dbuf
    __shared__ alignas(16) unsigned short Bs[2][64 * 64];    // 16 KB dbuf

    const int tid  = threadIdx.x;
    const int wv   = tid >> 6;
    const int lane = tid & 63;
    const int wm   = wv >> 1, wn = wv & 1;
    const int q4   = lane >> 4, l15 = lane & 15;

    // A staging: 4 chunks x (256 thr x 16B) = 128 rows x 64 cols
    const unsigned short* gA[4];
    int ldsAoff[4];             // wave-uniform LDS offsets (HW adds lane*16B)
#pragma unroll
    for (int j = 0; j < 4; j++) {
        const int r = wv * 32 + j * 8 + (lane >> 3);
        const int c = (((lane & 7) ^ (r & 7)) * 8);
        gA[j] = Aop + (long)(m0 + r) * K + c;
        ldsAoff[j] = (wv * 32 + j * 8) * 64;
    }
    // B staging: 2 chunks = 64 rows x 64 cols
    const unsigned short* gB[2];
    int ldsBoff[2];
#pragma unroll
    for (int j = 0; j < 2; j++) {
        const int r = j * 32 + wv * 8 + (lane >> 3);
        const int c = (((lane & 7) ^ (r & 7)) * 8);
        gB[j] = Bop + (long)(n0 + r) * K + c;
        ldsBoff[j] = (j * 32 + wv * 8) * 64;
    }

    int aoff[2][4], boff[2][2];
#pragma unroll
    for (int ks = 0; ks < 2; ks++) {
#pragma unroll
        for (int t = 0; t < 4; t++) {
            const int swzk = (((ks * 4 + q4) ^ (l15 & 7)) * 8);
            aoff[ks][t] = (wm * 64 + t * 16 + l15) * 64 + swzk;
        }
#pragma unroll
        for (int t = 0; t < 2; t++) {
            const int swzk = (((ks * 4 + q4) ^ (l15 & 7)) * 8);
            boff[ks][t] = (wn * 32 + t * 16 + l15) * 64 + swzk;
        }
    }

    float4v acc[4][2];
#pragma unroll
    for (int i = 0; i < 4; i++)
#pragma unroll
        for (int j = 0; j < 2; j++) acc[i][j] = (float4v)0.0f;

    // prologue: stage tile 0 into buf 0, then drain+barrier
#pragma unroll
    for (int j = 0; j < 4; j++) { async_cp16(gA[j], &As[0][ldsAoff[j]]); gA[j] += 64; }
#pragma unroll
    for (int j = 0; j < 2; j++) { async_cp16(gB[j], &Bs[0][ldsBoff[j]]); gB[j] += 64; }
    __syncthreads();

    for (int it = 0; it < NT; it++) {
        const int cur = it & 1;

        // issue NEXT tile's staging loads into buf^1 (in flight under compute)
        if (it + 1 < NT) {
#pragma unroll
            for (int j = 0; j < 4; j++) { async_cp16(gA[j], &As[cur ^ 1][ldsAoff[j]]); gA[j] += 64; }
#pragma unroll
            for (int j = 0; j < 2; j++) { async_cp16(gB[j], &Bs[cur ^ 1][ldsBoff[j]]); gB[j] += 64; }
        }

        // compute current tile from buf[cur]
#pragma unroll
        for (int ks = 0; ks < 2; ks++) {
            short8 afr[4], bfr[2];
#pragma unroll
            for (int mt = 0; mt < 4; mt++) afr[mt] = *(const short8*)&As[cur][aoff[ks][mt]];
#pragma unroll
            for (int nt = 0; nt < 2; nt++) bfr[nt] = *(const short8*)&Bs[cur][boff[ks][nt]];
#pragma unroll
            for (int mt = 0; mt < 4; mt++)
#pragma unroll
                for (int nt = 0; nt < 2; nt++)
                    acc[mt][nt] = __builtin_amdgcn_mfma_f32_16x16x32_bf16(
                        afr[mt], bfr[nt], acc[mt][nt], 0, 0, 0);
        }

        // drain (t+1 loads had the whole compute phase to land) + barrier
        __syncthreads();
    }

#pragma unroll
    for (int mt = 0; mt < 4; mt++)
#pragma unroll
        for (int nt = 0; nt < 2; nt++)
#pragma unroll
            for (int r = 0; r < 4; r++) {
                const int m = m0 + wm * 64 + mt * 16 + q4 * 4 + r;
                const int n = n0 + wn * 32 + nt * 16 + l15;
                float v = acc[mt][nt][r];
                if (mode == 3) {
                    ((float*)Op)[(long)m * D_ + n] = v;
                } else if (mode == 2) {
                    const long off = (((long)(n >> 11) * H_ + (m >> 6)) * HD_ + (m & 63)) * S_ + (n & 2047);
                    ((unsigned short*)Op)[off] = f_to_bf16bits(v);
                } else {
                    const long off = ((long)((m >> 11) * H_ + (n >> 6)) * S_ + (m & 2047)) * HD_ + (n & 63);
                    if (mode == 0) v *= PSCALE;
                    ((unsigned short*)Op)[off] = f_to_bf16bits(v);
                }
            }
}

// ---------------------------------------------------------------------------
// Flash attention (R10 winner, frozen): 512 thr / 8 waves, 128 q-rows per WG
// (1 m-tile per wave), 64x64 K/V dbuf, 1 barrier per k-tile, distance-1
// prefetch, LDS-P round-trip, setprio around MFMA clusters. 77us measured.
// ---------------------------------------------------------------------------
__global__ __launch_bounds__(512, 4) void attn(
    const unsigned short* __restrict__ Q,    // [B,H,S,HD], pre-scaled by PSCALE
    const unsigned short* __restrict__ Kk,   // [B,H,S,HD]
    const unsigned short* __restrict__ Vt,   // [B,H,HD,S]
    const float* __restrict__ mask,          // [S,S]
    unsigned short* __restrict__ ctx)        // [B,S,D]
{
    __shared__ alignas(16) unsigned short Ks [2][64 * 72];   // [buf][k_local][d]  18 KB
    __shared__ alignas(16) unsigned short Vts[2][64 * 72];   // [buf][d][k_local]  18 KB
    __shared__ alignas(16) unsigned short Ps [8][16 * 72];   // per-wave P        18.4 KB

    const int tid  = threadIdx.x;      // 0..511
    const int wv   = tid >> 6;         // 0..7
    const int lane = tid & 63;
    const int q4   = lane >> 4, l15 = lane & 15;
    const int bh   = blockIdx.y;
    const int q0   = blockIdx.x * 128;

    const long head = (long)bh * S_ * HD_;

    // Q fragment: wave owns rows q0 + wv*16 + l15 (one m-tile)
    const int qrow = q0 + wv * 16 + l15;
    short8 qfr[2];
    qfr[0] = *(const short8*)&Q[head + (long)qrow * HD_ + q4 * 8];
    qfr[1] = *(const short8*)&Q[head + (long)qrow * HD_ + 32 + q4 * 8];

    float l_acc[4] = {0.0f, 0.0f, 0.0f, 0.0f};
    float4v oacc[4];
#pragma unroll
    for (int dt = 0; dt < 4; dt++) oacc[dt] = (float4v)0.0f;

    // staging: 512 thr, K tile 64x64 + V tile 64x64, ONE 16B chunk each;
    // thread covers row tid/8, col (tid&7)*8
    const int srow = tid >> 3;         // 0..63
    const int scol = (tid & 7) * 8;    // 0..56
    const unsigned short* gK = Kk + head + (long)srow * HD_ + scol;
    const unsigned short* gV = Vt + head + (long)srow * S_  + scol;
    const int ldsOff = srow * 72 + scol;

    // per-thread mask row bases
    const float* mrow[4];
#pragma unroll
    for (int r = 0; r < 4; r++)
        mrow[r] = mask + (long)(q0 + wv * 16 + q4 * 4 + r) * S_ + l15;

    // distance-1 register prefetch (tile 0)
    int4v kreg = *(const int4v*)gK;
    int4v vreg = *(const int4v*)gV;

    for (int it = 0; it < S_ / 64; it++) {
        const int k0  = it * 64;
        const int buf = it & 1;

        // stage tile it into buf (regs were prefetched last iter)
        *(int4v*)&Ks [buf][ldsOff] = kreg;
        *(int4v*)&Vts[buf][ldsOff] = vreg;
        __syncthreads();   // single barrier per k-tile: buf fully staged

        // issue next tile's staging loads: in flight under compute below
        if (it + 1 < S_ / 64) {
            kreg = *(const int4v*)(gK + (long)(k0 + 64) * HD_);
            vreg = *(const int4v*)(gV + (k0 + 64));
        }

        // mask loads issued first (L2-hot): latency hidden under QK below
        float mv[4][4];
#pragma unroll
        for (int nt = 0; nt < 4; nt++)
#pragma unroll
            for (int r = 0; r < 4; r++)
                mv[nt][r] = mrow[r][k0 + nt * 16];

        // QK^T
        float4v sfr[4];
        __builtin_amdgcn_s_setprio(1);
#pragma unroll
        for (int nt = 0; nt < 4; nt++) {
            short8 kb0 = *(const short8*)&Ks[buf][(nt * 16 + l15) * 72 + q4 * 8];
            short8 kb1 = *(const short8*)&Ks[buf][(nt * 16 + l15) * 72 + 32 + q4 * 8];
            float4v s = (float4v)0.0f;
            s = __builtin_amdgcn_mfma_f32_16x16x32_bf16(qfr[0], kb0, s, 0, 0, 0);
            s = __builtin_amdgcn_mfma_f32_16x16x32_bf16(qfr[1], kb1, s, 0, 0, 0);
            sfr[nt] = s;
        }
        __builtin_amdgcn_s_setprio(0);

        // p = 2^(dot_scaled + mask*PSCALE); per-lane row sums; P -> LDS
#pragma unroll
        for (int nt = 0; nt < 4; nt++)
#pragma unroll
            for (int r = 0; r < 4; r++) {
                const float p = fast_exp2(fmaf(mv[nt][r], PSCALE, sfr[nt][r]));
                l_acc[r] += p;
                Ps[wv][(q4 * 4 + r) * 72 + nt * 16 + l15] = f_to_bf16bits(p);
            }

        // P fragment (A-layout); Ps is per-wave: no barrier needed
        short8 pf0 = *(const short8*)&Ps[wv][l15 * 72 + q4 * 8];
        short8 pf1 = *(const short8*)&Ps[wv][l15 * 72 + 32 + q4 * 8];

        // O += P V
        __builtin_amdgcn_s_setprio(1);
#pragma unroll
        for (int dt = 0; dt < 4; dt++) {
            short8 vb0 = *(const short8*)&Vts[buf][(dt * 16 + l15) * 72 + q4 * 8];
            short8 vb1 = *(const short8*)&Vts[buf][(dt * 16 + l15) * 72 + 32 + q4 * 8];
            float4v o = oacc[dt];
            o = __builtin_amdgcn_mfma_f32_16x16x32_bf16(pf0, vb0, o, 0, 0, 0);
            o = __builtin_amdgcn_mfma_f32_16x16x32_bf16(pf1, vb1, o, 0, 0, 0);
            oacc[dt] = o;
        }
        __builtin_amdgcn_s_setprio(0);
    }

    // butterfly over the 16 column-lanes
#pragma unroll
    for (int r = 0; r < 4; r++) {
#pragma unroll
        for (int off = 1; off < 16; off <<= 1)
            l_acc[r] += __shfl_xor(l_acc[r], off);
    }

    const int b = bh >> 4, h = bh & 15;
#pragma unroll
    for (int dt = 0; dt < 4; dt++)
#pragma unroll
        for (int r = 0; r < 4; r++) {
            const int qg = q0 + wv * 16 + q4 * 4 + r;
            const int d  = dt * 16 + l15;
            const float v = oacc[dt][r] / l_acc[r];
            ctx[((long)(b * S_ + qg)) * D_ + h * HD_ + d] = f_to_bf16bits(v);
        }
}

extern "C" void kernel_launch(void* const* d_in, const int* in_sizes, int n_in,
                              void* d_out, int out_size, void* d_ws, size_t ws_size,
                              hipStream_t stream) {
    const float* X    = (const float*)d_in[0];
    const float* mask = (const float*)d_in[1];
    const float* Wq   = (const float*)d_in[2];
    const float* Wk   = (const float*)d_in[3];
    const float* Wv   = (const float*)d_in[4];
    const float* Wo   = (const float*)d_in[5];
    float* out        = (float*)d_out;

    unsigned short* ws = (unsigned short*)d_ws;
    unsigned short* qws  = ws;                 // 4M elems each
    unsigned short* kws  = ws + 4194304;
    unsigned short* vtws = ws + 8388608;
    unsigned short* ctx  = ws + 12582912;
    unsigned short* Xb   = ws + 16777216;      // 4M
    unsigned short* Wqb  = ws + 20971520;      // 1M each
    unsigned short* Wkb  = ws + 22020096;
    unsigned short* Wvb  = ws + 23068672;
    unsigned short* Wob  = ws + 24117248;      // end = 48MB

    cvt_bf16<<<dim3(4096), 256, 0, stream>>>(X, Wq, Wk, Wv, Wo, Xb, Wqb, Wkb, Wvb, Wob);
    gemm_bt<<<dim3(32, 16, 3), 256, 0, stream>>>(Xb, Wqb, Wkb, Wvb, qws, kws, vtws, 0);
    attn<<<dim3(16, 32, 1), 512, 0, stream>>>(qws, kws, vtws, mask, ctx);
    gemm_bt<<<dim3(32, 16, 1), 256, 0, stream>>>(ctx, Wob, Wob, Wob, out, out, out, 3);
}

// Round 16
// 208.534 us; speedup vs baseline: 1.0337x; 1.0337x over previous
//
#include <hip/hip_runtime.h>

// Problem constants
#define B_  2
#define S_  2048
#define D_  1024
#define H_  16
#define HD_ 64
#define M_  (B_*S_)   // 4096

typedef __attribute__((ext_vector_type(8))) short  short8;   // 8 bf16 (4 VGPRs)
typedef __attribute__((ext_vector_type(4))) float  float4v;  // 4 fp32
typedef __attribute__((ext_vector_type(4))) int    int4v;    // 16B

// 1/sqrt(D) * log2(e): softmax via native exp2 (v_exp_f32)
#define PSCALE 0.0450843341f   // (1/32) * 1.4426950408889634

__device__ __forceinline__ unsigned int pack2_bf16(float a, float b) {
#if __has_builtin(__builtin_amdgcn_cvt_pk_bf16_f32)
    auto p = __builtin_amdgcn_cvt_pk_bf16_f32(a, b);   // 1 VALU op, RNE
    return __builtin_bit_cast(unsigned int, p);
#else
    unsigned int xa = __builtin_bit_cast(unsigned int, a);
    unsigned int xb = __builtin_bit_cast(unsigned int, b);
    xa += 0x7fffu + ((xa >> 16) & 1u);
    xb += 0x7fffu + ((xb >> 16) & 1u);
    return (xa >> 16) | (xb & 0xffff0000u);
#endif
}
__device__ __forceinline__ unsigned short f_to_bf16bits(float f) {
#if __has_builtin(__builtin_amdgcn_cvt_pk_bf16_f32)
    return (unsigned short)(pack2_bf16(f, f) & 0xffffu);
#else
    unsigned int x = __builtin_bit_cast(unsigned int, f);
    x += 0x7fffu + ((x >> 16) & 1u);
    return (unsigned short)(x >> 16);
#endif
}

__device__ __forceinline__ float fast_exp2(float x) {
#if __has_builtin(__builtin_amdgcn_exp2f)
    return __builtin_amdgcn_exp2f(x);
#else
    return exp2f(x);
#endif
}

// Async global->LDS copy, 16B per lane. HW semantics: LDS dest = WAVE-UNIFORM
// base + lane*16; global src is PER-LANE. Caller passes the uniform LDS base.
__device__ __forceinline__ void async_cp16(const unsigned short* gsrc,
                                           unsigned short* lds_base_uniform) {
#if __has_builtin(__builtin_amdgcn_global_load_lds)
    __builtin_amdgcn_global_load_lds(
        (const __attribute__((address_space(1))) unsigned int*)gsrc,
        (__attribute__((address_space(3))) unsigned int*)lds_base_uniform,
        16, 0, 0);
#else
    const int lane = (int)(threadIdx.x & 63);
    *(int4v*)(lds_base_uniform + lane * 8) = *(const int4v*)gsrc;
#endif
}

// ---------------------------------------------------------------------------
// fp32 -> bf16 bulk convert: X(4M) + Wq,Wk,Wv,Wo (1M each). 8 elems/thread.
// ---------------------------------------------------------------------------
__global__ __launch_bounds__(256) void cvt_bf16(
    const float* __restrict__ X,  const float* __restrict__ Wq,
    const float* __restrict__ Wk, const float* __restrict__ Wv,
    const float* __restrict__ Wo,
    unsigned short* __restrict__ Xb,  unsigned short* __restrict__ Wqb,
    unsigned short* __restrict__ Wkb, unsigned short* __restrict__ Wvb,
    unsigned short* __restrict__ Wob)
{
    const long t = (long)blockIdx.x * 256 + threadIdx.x;
    const long e = t * 8;
    const float* src; unsigned short* dst; long off;
    if      (e < 4194304) { src = X;  dst = Xb;  off = e; }
    else if (e < 5242880) { src = Wq; dst = Wqb; off = e - 4194304; }
    else if (e < 6291456) { src = Wk; dst = Wkb; off = e - 5242880; }
    else if (e < 7340032) { src = Wv; dst = Wvb; off = e - 6291456; }
    else                  { src = Wo; dst = Wob; off = e - 7340032; }
    float4v a = *(const float4v*)&src[off];
    float4v b = *(const float4v*)&src[off + 4];
    int4v o;
    o[0] = (int)pack2_bf16(a[0], a[1]);
    o[1] = (int)pack2_bf16(a[2], a[3]);
    o[2] = (int)pack2_bf16(b[0], b[1]);
    o[3] = (int)pack2_bf16(b[2], b[3]);
    *(int4v*)&dst[off] = o;
}

// ---------------------------------------------------------------------------
// NT GEMM (R16 = exact R11 revert, the best-measured config: 208.6us total).
// Tile 128x64, BK=64, global_load_lds staging, 1-phase (two barriers/K-step).
// R13 (64x64), R14 (+swizzle), R15 (2-phase dbuf) all measured neutral or
// negative vs this: the gemm's hiding mechanism is wave-TLP at 6 WG/CU, and
// every structural lever beyond that is exhausted at this tile density.
//   QKV:  (32,16,3) = 1536 WGs = 6 WG/CU = 24 waves/CU
//   gemm1:(32,16,1) =  512 WGs = 2 WG/CU
// LDS 24 KB (As 16K + Bs 8K). acc per wave 4x2 (32 VGPR).
// mode 0: Q  out[((b*H+h)*S+s)*HD+hd] * PSCALE
// mode 1: K  same layout, unscaled
// mode 2: Vt out[((b*H+h)*HD+hd)*S+s] -- operands SWAPPED (A=Wv, B=X);
//         grid decoded flat: 8 m-tiles x 64 n-tiles = 512 WGs
// mode 3: fp32 row-major out[m*D+n]
// ---------------------------------------------------------------------------
__global__ __launch_bounds__(256) void gemm_bt(
    const unsigned short* __restrict__ A,
    const unsigned short* __restrict__ B0,
    const unsigned short* __restrict__ B1,
    const unsigned short* __restrict__ B2,
    void* __restrict__ O0, void* __restrict__ O1, void* __restrict__ O2,
    int mode_base)
{
    const int K = 1024;
    const int z = blockIdx.z;
    const int mode = mode_base + z;
    const unsigned short* Aop;
    const unsigned short* Bop;
    void* Op = (z == 0) ? O0 : (z == 1) ? O1 : O2;
    int m0, n0;
    if (mode == 2) {            // swapped: A=Wv (rows=out-dim), B=X (rows=s)
        Aop = B2; Bop = A;
        const int flat = blockIdx.y * 32 + blockIdx.x;   // 0..511
        m0 = (flat & 7) * 128;                           // 8 m-tiles (1024)
        n0 = (flat >> 3) * 64;                           // 64 n-tiles (4096)
    } else {
        Aop = A;
        Bop = (z == 0) ? B0 : (z == 1) ? B1 : B2;
        m0 = blockIdx.x * 128;                           // 32 m-tiles (4096)
        n0 = blockIdx.y * 64;                            // 16 n-tiles (1024)
    }

    __shared__ alignas(16) unsigned short As[128 * 64];   // 16 KB
    __shared__ alignas(16) unsigned short Bs[64 * 64];    //  8 KB

    const int tid  = threadIdx.x;
    const int wv   = tid >> 6;
    const int lane = tid & 63;
    const int wm   = wv >> 1, wn = wv & 1;
    const int q4   = lane >> 4, l15 = lane & 15;

    // A staging: 4 chunks x (256 thr x 16B) = 128 rows x 64 cols
    const unsigned short* gA[4];
    unsigned short* ldsA[4];    // wave-uniform LDS bases (HW adds lane*16B)
#pragma unroll
    for (int j = 0; j < 4; j++) {
        const int r = wv * 32 + j * 8 + (lane >> 3);
        const int c = (((lane & 7) ^ (r & 7)) * 8);
        gA[j] = Aop + (long)(m0 + r) * K + c;
        ldsA[j] = &As[(wv * 32 + j * 8) * 64];
    }
    // B staging: 2 chunks = 64 rows x 64 cols
    const unsigned short* gB[2];
    unsigned short* ldsB[2];
#pragma unroll
    for (int j = 0; j < 2; j++) {
        const int r = j * 32 + wv * 8 + (lane >> 3);
        const int c = (((lane & 7) ^ (r & 7)) * 8);
        gB[j] = Bop + (long)(n0 + r) * K + c;
        ldsB[j] = &Bs[(j * 32 + wv * 8) * 64];
    }

    int aoff[2][4], boff[2][2];
#pragma unroll
    for (int ks = 0; ks < 2; ks++) {
#pragma unroll
        for (int t = 0; t < 4; t++) {
            const int swz = (((ks * 4 + q4) ^ (l15 & 7)) * 8);
            aoff[ks][t] = (wm * 64 + t * 16 + l15) * 64 + swz;
        }
#pragma unroll
        for (int t = 0; t < 2; t++) {
            const int swz = (((ks * 4 + q4) ^ (l15 & 7)) * 8);
            boff[ks][t] = (wn * 32 + t * 16 + l15) * 64 + swz;
        }
    }

    float4v acc[4][2];
#pragma unroll
    for (int i = 0; i < 4; i++)
#pragma unroll
        for (int j = 0; j < 2; j++) acc[i][j] = (float4v)0.0f;

    for (int k0 = 0; k0 < K; k0 += 64) {
        __syncthreads();   // prev-iter LDS reads done (WAR)
#pragma unroll
        for (int j = 0; j < 4; j++) { async_cp16(gA[j], ldsA[j]); gA[j] += 64; }
#pragma unroll
        for (int j = 0; j < 2; j++) { async_cp16(gB[j], ldsB[j]); gB[j] += 64; }
        __syncthreads();   // drains vmcnt: tile staged

#pragma unroll
        for (int ks = 0; ks < 2; ks++) {
            short8 afr[4], bfr[2];
#pragma unroll
            for (int mt = 0; mt < 4; mt++) afr[mt] = *(const short8*)&As[aoff[ks][mt]];
#pragma unroll
            for (int nt = 0; nt < 2; nt++) bfr[nt] = *(const short8*)&Bs[boff[ks][nt]];
#pragma unroll
            for (int mt = 0; mt < 4; mt++)
#pragma unroll
                for (int nt = 0; nt < 2; nt++)
                    acc[mt][nt] = __builtin_amdgcn_mfma_f32_16x16x32_bf16(
                        afr[mt], bfr[nt], acc[mt][nt], 0, 0, 0);
        }
    }

#pragma unroll
    for (int mt = 0; mt < 4; mt++)
#pragma unroll
        for (int nt = 0; nt < 2; nt++)
#pragma unroll
            for (int r = 0; r < 4; r++) {
                const int m = m0 + wm * 64 + mt * 16 + q4 * 4 + r;
                const int n = n0 + wn * 32 + nt * 16 + l15;
                float v = acc[mt][nt][r];
                if (mode == 3) {
                    ((float*)Op)[(long)m * D_ + n] = v;
                } else if (mode == 2) {
                    const long off = (((long)(n >> 11) * H_ + (m >> 6)) * HD_ + (m & 63)) * S_ + (n & 2047);
                    ((unsigned short*)Op)[off] = f_to_bf16bits(v);
                } else {
                    const long off = ((long)((m >> 11) * H_ + (n >> 6)) * S_ + (m & 2047)) * HD_ + (n & 63);
                    if (mode == 0) v *= PSCALE;
                    ((unsigned short*)Op)[off] = f_to_bf16bits(v);
                }
            }
}

// ---------------------------------------------------------------------------
// Flash attention (R10 winner, frozen): 512 thr / 8 waves, 128 q-rows per WG
// (1 m-tile per wave), 64x64 K/V dbuf, 1 barrier per k-tile, distance-1
// prefetch, LDS-P round-trip, setprio around MFMA clusters. 77us measured.
// ---------------------------------------------------------------------------
__global__ __launch_bounds__(512, 4) void attn(
    const unsigned short* __restrict__ Q,    // [B,H,S,HD], pre-scaled by PSCALE
    const unsigned short* __restrict__ Kk,   // [B,H,S,HD]
    const unsigned short* __restrict__ Vt,   // [B,H,HD,S]
    const float* __restrict__ mask,          // [S,S]
    unsigned short* __restrict__ ctx)        // [B,S,D]
{
    __shared__ alignas(16) unsigned short Ks [2][64 * 72];   // [buf][k_local][d]  18 KB
    __shared__ alignas(16) unsigned short Vts[2][64 * 72];   // [buf][d][k_local]  18 KB
    __shared__ alignas(16) unsigned short Ps [8][16 * 72];   // per-wave P        18.4 KB

    const int tid  = threadIdx.x;      // 0..511
    const int wv   = tid >> 6;         // 0..7
    const int lane = tid & 63;
    const int q4   = lane >> 4, l15 = lane & 15;
    const int bh   = blockIdx.y;
    const int q0   = blockIdx.x * 128;

    const long head = (long)bh * S_ * HD_;

    // Q fragment: wave owns rows q0 + wv*16 + l15 (one m-tile)
    const int qrow = q0 + wv * 16 + l15;
    short8 qfr[2];
    qfr[0] = *(const short8*)&Q[head + (long)qrow * HD_ + q4 * 8];
    qfr[1] = *(const short8*)&Q[head + (long)qrow * HD_ + 32 + q4 * 8];

    float l_acc[4] = {0.0f, 0.0f, 0.0f, 0.0f};
    float4v oacc[4];
#pragma unroll
    for (int dt = 0; dt < 4; dt++) oacc[dt] = (float4v)0.0f;

    // staging: 512 thr, K tile 64x64 + V tile 64x64, ONE 16B chunk each;
    // thread covers row tid/8, col (tid&7)*8
    const int srow = tid >> 3;         // 0..63
    const int scol = (tid & 7) * 8;    // 0..56
    const unsigned short* gK = Kk + head + (long)srow * HD_ + scol;
    const unsigned short* gV = Vt + head + (long)srow * S_  + scol;
    const int ldsOff = srow * 72 + scol;

    // per-thread mask row bases
    const float* mrow[4];
#pragma unroll
    for (int r = 0; r < 4; r++)
        mrow[r] = mask + (long)(q0 + wv * 16 + q4 * 4 + r) * S_ + l15;

    // distance-1 register prefetch (tile 0)
    int4v kreg = *(const int4v*)gK;
    int4v vreg = *(const int4v*)gV;

    for (int it = 0; it < S_ / 64; it++) {
        const int k0  = it * 64;
        const int buf = it & 1;

        // stage tile it into buf (regs were prefetched last iter)
        *(int4v*)&Ks [buf][ldsOff] = kreg;
        *(int4v*)&Vts[buf][ldsOff] = vreg;
        __syncthreads();   // single barrier per k-tile: buf fully staged

        // issue next tile's staging loads: in flight under compute below
        if (it + 1 < S_ / 64) {
            kreg = *(const int4v*)(gK + (long)(k0 + 64) * HD_);
            vreg = *(const int4v*)(gV + (k0 + 64));
        }

        // mask loads issued first (L2-hot): latency hidden under QK below
        float mv[4][4];
#pragma unroll
        for (int nt = 0; nt < 4; nt++)
#pragma unroll
            for (int r = 0; r < 4; r++)
                mv[nt][r] = mrow[r][k0 + nt * 16];

        // QK^T
        float4v sfr[4];
        __builtin_amdgcn_s_setprio(1);
#pragma unroll
        for (int nt = 0; nt < 4; nt++) {
            short8 kb0 = *(const short8*)&Ks[buf][(nt * 16 + l15) * 72 + q4 * 8];
            short8 kb1 = *(const short8*)&Ks[buf][(nt * 16 + l15) * 72 + 32 + q4 * 8];
            float4v s = (float4v)0.0f;
            s = __builtin_amdgcn_mfma_f32_16x16x32_bf16(qfr[0], kb0, s, 0, 0, 0);
            s = __builtin_amdgcn_mfma_f32_16x16x32_bf16(qfr[1], kb1, s, 0, 0, 0);
            sfr[nt] = s;
        }
        __builtin_amdgcn_s_setprio(0);

        // p = 2^(dot_scaled + mask*PSCALE); per-lane row sums; P -> LDS
#pragma unroll
        for (int nt = 0; nt < 4; nt++)
#pragma unroll
            for (int r = 0; r < 4; r++) {
                const float p = fast_exp2(fmaf(mv[nt][r], PSCALE, sfr[nt][r]));
                l_acc[r] += p;
                Ps[wv][(q4 * 4 + r) * 72 + nt * 16 + l15] = f_to_bf16bits(p);
            }

        // P fragment (A-layout); Ps is per-wave: no barrier needed
        short8 pf0 = *(const short8*)&Ps[wv][l15 * 72 + q4 * 8];
        short8 pf1 = *(const short8*)&Ps[wv][l15 * 72 + 32 + q4 * 8];

        // O += P V
        __builtin_amdgcn_s_setprio(1);
#pragma unroll
        for (int dt = 0; dt < 4; dt++) {
            short8 vb0 = *(const short8*)&Vts[buf][(dt * 16 + l15) * 72 + q4 * 8];
            short8 vb1 = *(const short8*)&Vts[buf][(dt * 16 + l15) * 72 + 32 + q4 * 8];
            float4v o = oacc[dt];
            o = __builtin_amdgcn_mfma_f32_16x16x32_bf16(pf0, vb0, o, 0, 0, 0);
            o = __builtin_amdgcn_mfma_f32_16x16x32_bf16(pf1, vb1, o, 0, 0, 0);
            oacc[dt] = o;
        }
        __builtin_amdgcn_s_setprio(0);
    }

    // butterfly over the 16 column-lanes
#pragma unroll
    for (int r = 0; r < 4; r++) {
#pragma unroll
        for (int off = 1; off < 16; off <<= 1)
            l_acc[r] += __shfl_xor(l_acc[r], off);
    }

    const int b = bh >> 4, h = bh & 15;
#pragma unroll
    for (int dt = 0; dt < 4; dt++)
#pragma unroll
        for (int r = 0; r < 4; r++) {
            const int qg = q0 + wv * 16 + q4 * 4 + r;
            const int d  = dt * 16 + l15;
            const float v = oacc[dt][r] / l_acc[r];
            ctx[((long)(b * S_ + qg)) * D_ + h * HD_ + d] = f_to_bf16bits(v);
        }
}

extern "C" void kernel_launch(void* const* d_in, const int* in_sizes, int n_in,
                              void* d_out, int out_size, void* d_ws, size_t ws_size,
                              hipStream_t stream) {
    const float* X    = (const float*)d_in[0];
    const float* mask = (const float*)d_in[1];
    const float* Wq   = (const float*)d_in[2];
    const float* Wk   = (const float*)d_in[3];
    const float* Wv   = (const float*)d_in[4];
    const float* Wo   = (const float*)d_in[5];
    float* out        = (float*)d_out;

    unsigned short* ws = (unsigned short*)d_ws;
    unsigned short* qws  = ws;                 // 4M elems each
    unsigned short* kws  = ws + 4194304;
    unsigned short* vtws = ws + 8388608;
    unsigned short* ctx  = ws + 12582912;
    unsigned short* Xb   = ws + 16777216;      // 4M
    unsigned short* Wqb  = ws + 20971520;      // 1M each
    unsigned short* Wkb  = ws + 22020096;
    unsigned short* Wvb  = ws + 23068672;
    unsigned short* Wob  = ws + 24117248;      // end = 48MB

    cvt_bf16<<<dim3(4096), 256, 0, stream>>>(X, Wq, Wk, Wv, Wo, Xb, Wqb, Wkb, Wvb, Wob);
    gemm_bt<<<dim3(32, 16, 3), 256, 0, stream>>>(Xb, Wqb, Wkb, Wvb, qws, kws, vtws, 0);
    attn<<<dim3(16, 32, 1), 512, 0, stream>>>(qws, kws, vtws, mask, ctx);
    gemm_bt<<<dim3(32, 16, 1), 256, 0, stream>>>(ctx, Wob, Wob, Wob, out, out, out, 3);
}